// Round 5
// baseline (2719.033 us; speedup 1.0000x reference)
//
#include <hip/hip_runtime.h>
#include <stdint.h>
#include <math.h>

// ---------------------------------------------------------------------------
// DecoderRNN: 2-layer LSTM (B=32, T=64, E=H=512) + vocab projection (V=50257)
//
//   K1  build_inputs : gather -> inputs_bf, COMPACT layout [t][slice][b][16]
//   K2  cast weights to bf16, pad-cast w_out
//   K3  lstm_pipeline: persistent, 64 WGs (32/layer). Weights in LDS.
//       h exchange: compact layout, __hip_atomic_exchange (L3-ack) stores,
//       sc0sc1 bypass loads, 4-stage pipelined (vmcnt(8) cadence).
//       Slot-signal sync (64B-padded words), layer-0 free-runs.
//       Same kernel re-launched as a SYNC-FREE PROBE (dosync=0, 8x65 steps,
//       private buffers) purely to measure the compute floor via rocprof.
//   K4  logits_gemm  : 128x128x32 bf16 MFMA GEMM (m97 structure).
// ---------------------------------------------------------------------------

typedef unsigned short u16;
typedef __bf16 bf16x8 __attribute__((ext_vector_type(8)));
typedef float  f32x4  __attribute__((ext_vector_type(4)));

#define BATCH   32
#define SEQT    64
#define NSTEP   65
#define EMB     512
#define HID     512
#define VOCAB   50257
#define VPAD    50304         // 393*128
#define NWG_LSTM 64

// dynamic LDS layout (bytes)
#define LDS_GATES   131072    // float[4][32][16] = 8192
#define LDS_C       139264    // float[32][16]    = 2048
#define LDS_BIAS    141312    // float[4][16]     = 256
#define LDS_TOTAL   141568

static __device__ __forceinline__ u16 f2bf(float f) {
  unsigned u = __float_as_uint(f);
  u += 0x7FFFu + ((u >> 16) & 1u);
  return (u16)(u >> 16);
}

// Coherent-point (bypass L1+L2) 16B load. Validity only after manual vmcnt.
static __device__ __forceinline__ bf16x8 ld_frag_sys(const u16* p16) {
  union { uint4 u; bf16x8 v; } f;
  asm volatile("global_load_dwordx4 %0, %1, off sc0 sc1"
               : "=v"(f.u) : "v"(p16));
  return f.v;
}

static __device__ __forceinline__ float sigmoid_fast(float x) {
  return 1.0f / (1.0f + __expf(-x));
}
static __device__ __forceinline__ float tanh_fast(float x) {
  return 1.0f - 2.0f / (__expf(2.0f * x) + 1.0f);
}

// 32-lane slot poll (call from wave 0, then __syncthreads()).
static __device__ __forceinline__ void poll_slots(const unsigned* slots,
                                                  int base_slot, unsigned tgt,
                                                  int lane) {
  const unsigned* p = slots + (base_slot + (lane & 31)) * 16;
  for (;;) {
    unsigned v = __hip_atomic_load(p, __ATOMIC_RELAXED, __HIP_MEMORY_SCOPE_AGENT);
    if (__all((int)(v >= tgt))) break;
    __builtin_amdgcn_s_sleep(1);
  }
}

// ---------------------------------------------------------------------------
// K1: compact layout dst[t][e>>4][b][e&15]
// ---------------------------------------------------------------------------
__global__ void build_inputs(const float* __restrict__ features,
                             const int*   __restrict__ captions,
                             const float* __restrict__ embed_w,
                             u16* __restrict__ dst) {
  int idx = blockIdx.x * blockDim.x + threadIdx.x;
  const int n = NSTEP * BATCH * EMB;
  if (idx >= n) return;
  int e = idx & (EMB - 1);
  int rem = idx >> 9;
  int b = rem & (BATCH - 1);
  int t = rem >> 5;
  float v;
  if (t == 0) v = features[b * EMB + e];
  else        v = embed_w[(size_t)captions[b * SEQT + (t - 1)] * EMB + e];
  dst[(size_t)t * 16384 + (e >> 4) * 512 + b * 16 + (e & 15)] = f2bf(v);
}

// ---------------------------------------------------------------------------
// K2
// ---------------------------------------------------------------------------
__global__ void cast_bf16(const float* __restrict__ src, u16* __restrict__ dst, int n4) {
  int i = blockIdx.x * blockDim.x + threadIdx.x;
  if (i >= n4) return;
  float4 v = ((const float4*)src)[i];
  ushort4 o;
  o.x = f2bf(v.x); o.y = f2bf(v.y); o.z = f2bf(v.z); o.w = f2bf(v.w);
  ((ushort4*)dst)[i] = o;
}

__global__ void cast_pad_wout(const float* __restrict__ src, u16* __restrict__ dst) {
  int i = blockIdx.x * blockDim.x + threadIdx.x;
  const int n4 = VPAD * 512 / 4;
  const int nsrc4 = VOCAB * 512 / 4;
  if (i >= n4) return;
  ushort4 o;
  if (i < nsrc4) {
    float4 v = ((const float4*)src)[i];
    o.x = f2bf(v.x); o.y = f2bf(v.y); o.z = f2bf(v.z); o.w = f2bf(v.w);
  } else {
    o.x = 0; o.y = 0; o.z = 0; o.w = 0;
  }
  ((ushort4*)dst)[i] = o;
}

// ---------------------------------------------------------------------------
// K3
// ---------------------------------------------------------------------------
#define WAIT_VM_8 do { asm volatile("s_waitcnt vmcnt(8)" ::: "memory"); \
                       __builtin_amdgcn_sched_barrier(0); } while (0)
#define WAIT_VM_0 do { asm volatile("s_waitcnt vmcnt(0)" ::: "memory"); \
                       __builtin_amdgcn_sched_barrier(0); } while (0)

#define ISSUE_G(BUF, G, HB)                                                   \
  _Pragma("unroll")                                                           \
  for (int i = 0; i < 4; ++i) {                                               \
    s0[BUF][i] = ld_frag_sys((const u16*)((HB) + ((G) * 4 + i) * 2048 + loff0)); \
    s1[BUF][i] = ld_frag_sys((const u16*)((HB) + ((G) * 4 + i) * 2048 + loff1)); \
  }

#define CONSUME_G(BUF, G, WOFF)                                               \
  _Pragma("unroll")                                                           \
  for (int i = 0; i < 4; ++i) {                                               \
    const int kk = (G) * 4 + i;                                               \
    union { uint4 u; bf16x8 v; } w;                                           \
    w.u = *(const uint4*)(wv_base + (WOFF) + rowbase + ((kk * 64 + lgoff) ^ swz)); \
    acc0 = __builtin_amdgcn_mfma_f32_16x16x32_bf16(s0[BUF][i], w.v, acc0, 0, 0, 0); \
    acc1 = __builtin_amdgcn_mfma_f32_16x16x32_bf16(s1[BUF][i], w.v, acc1, 0, 0, 0); \
  }

// 4-group pipelined phase: loads bypass caches, weights from LDS.
#define SYS_PHASE(HB, WOFF)                                                   \
  {                                                                           \
    bf16x8 s0[2][4], s1[2][4];                                                \
    ISSUE_G(0, 0, HB)                                                         \
    ISSUE_G(1, 1, HB)                                                         \
    WAIT_VM_8; CONSUME_G(0, 0, WOFF) ISSUE_G(0, 2, HB)                        \
    WAIT_VM_8; CONSUME_G(1, 1, WOFF) ISSUE_G(1, 3, HB)                        \
    WAIT_VM_8; CONSUME_G(0, 2, WOFF)                                          \
    WAIT_VM_0; CONSUME_G(1, 3, WOFF)                                          \
  }

__global__ __launch_bounds__(256)
void lstm_pipeline(const u16* __restrict__ inputs_bf,   // [65][32sl][32b][16]
                   const u16* __restrict__ wih0, const u16* __restrict__ whh0,
                   const float* __restrict__ b0,
                   const u16* __restrict__ wih1, const u16* __restrict__ whh1,
                   const float* __restrict__ b1,
                   u16* h0_all,                  // [65][32sl][32b][16]
                   u16* h1_all,
                   u16* __restrict__ A_bf,       // [2048][512] rows (b*64+t)
                   unsigned* slots,              // [64] x 16 u32
                   int nloops, int dosync) {
  const int wg    = blockIdx.x;
  const int layer = wg >> 5;
  const int jsl   = wg & 31;
  const int j0    = jsl * 16;
  const int tid   = threadIdx.x;
  const int lane  = tid & 63;
  const int wv    = tid >> 6;       // wave index == gate index
  const int l15   = lane & 15;
  const int lg    = lane >> 4;

  const u16*   wih  = layer ? wih1 : wih0;
  const u16*   whh  = layer ? whh1 : whh0;
  const float* bias = layer ? b1 : b0;
  const char* xsrc  = (const char*)(layer ? h0_all : inputs_bf);
  const char* hsrc  = (const char*)(layer ? h1_all : h0_all);
  u16*        hdst  = layer ? h1_all : h0_all;
  const int own_base = layer ? 32 : 0;

  extern __shared__ char smem[];
  float* gates_l = (float*)(smem + LDS_GATES);
  float* c_l     = (float*)(smem + LDS_C);
  float* bias_l  = (float*)(smem + LDS_BIAS);

  for (int i = tid; i < BATCH * 16; i += 256) c_l[i] = 0.0f;
  if (tid < 64) bias_l[tid] = bias[(tid >> 4) * HID + j0 + (tid & 15)];

  // stage weights into LDS (swizzled), one-time
  {
    char* wbase = smem + wv * 32768;
    const u16* g0 = wih + (size_t)(wv * HID + j0) * 512;
    const u16* g1 = whh + (size_t)(wv * HID + j0) * 512;
#pragma unroll
    for (int m = 0; m < 2; ++m) {
      char* lbase = wbase + m * 16384;
      const u16* g = m ? g1 : g0;
#pragma unroll
      for (int c = 0; c < 16; ++c) {
        int q   = lane + 64 * c;
        int row = q >> 6;
        int k16 = q & 63;
        uint4 v = *(const uint4*)(g + (size_t)row * 512 + k16 * 8);
        int boff = row * 1024 + ((k16 * 16) ^ ((row & 7) << 4));
        *(uint4*)(lbase + boff) = v;
      }
    }
  }
  __syncthreads();

  const char* wv_base = smem + wv * 32768;
  const int   rowbase = l15 * 1024;
  const int   swz     = (l15 & 7) << 4;
  const int   lgoff   = lg * 16;
  // compact-layout lane offsets: frag(b, k0=kk*32+8*lg) at
  // (k0>>4)*1024 + b*32 + (k0&15)*2
  const int   loff0   = (lg >> 1) * 1024 + l15 * 32 + (lg & 1) * 16;
  const int   loff1   = loff0 + 512;    // b + 16

  for (int L = 0; L < nloops; ++L) {
    for (int t = 0; t < NSTEP; ++t) {
      // ---------------- X phase ----------------
      if (dosync && layer == 1) {
        if (tid < 64) poll_slots(slots, 0, (unsigned)(t + 1), lane);
        __syncthreads();
      }
      f32x4 acc0 = {0.f, 0.f, 0.f, 0.f};
      f32x4 acc1 = {0.f, 0.f, 0.f, 0.f};
      {
        const char* hb = xsrc + (size_t)t * 32768;
        SYS_PHASE(hb, 0)
      }
      // ---------------- H phase ----------------
      if (t > 0) {
        if (dosync) {
          if (tid < 64) poll_slots(slots, own_base, (unsigned)t, lane);
          __syncthreads();
        }
        const char* hb = hsrc + (size_t)(t - 1) * 32768;
        SYS_PHASE(hb, 16384)
      }
      // C layout: col = lane&15, row = 4*(lane>>4)+reg
#pragma unroll
      for (int rr = 0; rr < 4; ++rr) {
        gates_l[wv * 512 + (4 * lg + rr) * 16 + l15]      = acc0[rr];
        gates_l[wv * 512 + (16 + 4 * lg + rr) * 16 + l15] = acc1[rr];
      }
      __syncthreads();

      if (tid < 128) {
        const int b = tid >> 2;
        const int q = (tid & 3) * 4;
        float hv[4];
#pragma unroll
        for (int u = 0; u < 4; ++u) {
          const int jj = q + u;
          float gi = gates_l[0 * 512 + b * 16 + jj] + bias_l[0 * 16 + jj];
          float gf = gates_l[1 * 512 + b * 16 + jj] + bias_l[1 * 16 + jj];
          float gg = gates_l[2 * 512 + b * 16 + jj] + bias_l[2 * 16 + jj];
          float go = gates_l[3 * 512 + b * 16 + jj] + bias_l[3 * 16 + jj];
          float cp = c_l[b * 16 + jj];
          float cn = sigmoid_fast(gf) * cp + sigmoid_fast(gi) * tanh_fast(gg);
          c_l[b * 16 + jj] = cn;
          hv[u] = sigmoid_fast(go) * tanh_fast(cn);
        }
        union { ushort4 s; unsigned long long v; } pk;
        pk.s.x = f2bf(hv[0]); pk.s.y = f2bf(hv[1]);
        pk.s.z = f2bf(hv[2]); pk.s.w = f2bf(hv[3]);
        // h store: atomic exchange -> executes/acks at coherence point (L3)
        unsigned long long* hp = (unsigned long long*)
            ((char*)hdst + (size_t)t * 32768 + jsl * 1024 + b * 32 + (tid & 3) * 8);
        (void)__hip_atomic_exchange(hp, pk.v, __ATOMIC_RELAXED,
                                    __HIP_MEMORY_SCOPE_AGENT);
        if (layer == 1 && t >= 1)
          *(unsigned long long*)(A_bf + (size_t)(b * SEQT + (t - 1)) * HID + j0 + q) = pk.v;
      }
      // drain own exchanges (L3 ack, not HBM), then signal
      asm volatile("s_waitcnt vmcnt(0)" ::: "memory");
      __syncthreads();
      if (tid == 0)
        (void)__hip_atomic_exchange(&slots[wg * 16], (unsigned)(t + 1),
                                    __ATOMIC_RELAXED, __HIP_MEMORY_SCOPE_AGENT);
    }
  }
}

// ---------------------------------------------------------------------------
// K4: logits GEMM (unchanged).
// ---------------------------------------------------------------------------
static __device__ __forceinline__ bf16x8 ld_frag(const u16* p16) {
  union { uint4 u; bf16x8 v; } f;
  f.u = *(const uint4*)p16;
  return f.v;
}

__global__ __launch_bounds__(256)
void logits_gemm(const u16* __restrict__ Ag,
                 const u16* __restrict__ Bg,
                 const float* __restrict__ b_out,
                 float* __restrict__ out) {
  const int mt = blockIdx.x;
  const int nt = blockIdx.y;
  const int m0 = mt * 128, v0 = nt * 128;
  const int tid  = threadIdx.x;
  const int lane = tid & 63;
  const int wv   = tid >> 6;
  const int l15  = lane & 15;
  const int lg   = lane >> 4;
  const int wm = (wv & 1) * 64;
  const int wn = (wv >> 1) * 64;

  __shared__ u16 As[128 * 32];
  __shared__ u16 Bs[128 * 32];

  f32x4 acc[4][4];
#pragma unroll
  for (int mi = 0; mi < 4; ++mi)
#pragma unroll
    for (int ni = 0; ni < 4; ++ni)
      acc[mi][ni] = (f32x4){0.f, 0.f, 0.f, 0.f};

  for (int kt = 0; kt < 16; ++kt) {
#pragma unroll
    for (int c = 0; c < 2; ++c) {
      int f16 = wv * 128 + c * 64 + lane;
      int row = f16 >> 2;
      int kc  = (f16 & 3) << 3;
      const u16* ga = Ag + (size_t)(m0 + row) * 512 + kt * 32 + kc;
      const u16* gb = Bg + (size_t)(v0 + row) * 512 + kt * 32 + kc;
      u16* la = &As[(wv * 128 + c * 64) * 8];
      u16* lb = &Bs[(wv * 128 + c * 64) * 8];
      __builtin_amdgcn_global_load_lds(
          (const __attribute__((address_space(1))) void*)ga,
          (__attribute__((address_space(3))) void*)la, 16, 0, 0);
      __builtin_amdgcn_global_load_lds(
          (const __attribute__((address_space(1))) void*)gb,
          (__attribute__((address_space(3))) void*)lb, 16, 0, 0);
    }
    asm volatile("s_waitcnt vmcnt(0)" ::: "memory");
    __syncthreads();

    bf16x8 af[4], bfr[4];
#pragma unroll
    for (int i = 0; i < 4; ++i) {
      af[i]  = ld_frag(&As[(wm + i * 16 + l15) * 32 + 8 * lg]);
      bfr[i] = ld_frag(&Bs[(wn + i * 16 + l15) * 32 + 8 * lg]);
    }
#pragma unroll
    for (int mi = 0; mi < 4; ++mi)
#pragma unroll
      for (int ni = 0; ni < 4; ++ni)
        acc[mi][ni] = __builtin_amdgcn_mfma_f32_16x16x32_bf16(af[mi], bfr[ni], acc[mi][ni], 0, 0, 0);
    __syncthreads();
  }

#pragma unroll
  for (int ni = 0; ni < 4; ++ni) {
    int v = v0 + wn + ni * 16 + l15;
    bool vok = (v < VOCAB);
    float bo = vok ? b_out[v] : 0.0f;
#pragma unroll
    for (int mi = 0; mi < 4; ++mi) {
      int mbase = m0 + wm + mi * 16 + 4 * lg;
#pragma unroll
      for (int rr = 0; rr < 4; ++rr) {
        if (vok) out[(size_t)(mbase + rr) * VOCAB + v] = acc[mi][ni][rr] + bo;
      }
    }
  }
}

// ---------------------------------------------------------------------------
// host
// ---------------------------------------------------------------------------
extern "C" void kernel_launch(void* const* d_in, const int* in_sizes, int n_in,
                              void* d_out, int out_size, void* d_ws, size_t ws_size,
                              hipStream_t stream) {
  const float* features = (const float*)d_in[0];
  const int*   captions = (const int*)d_in[1];
  const float* embed_w  = (const float*)d_in[2];
  const float* w_ih0    = (const float*)d_in[3];
  const float* w_hh0    = (const float*)d_in[4];
  const float* b0       = (const float*)d_in[5];
  const float* w_ih1    = (const float*)d_in[6];
  const float* w_hh1    = (const float*)d_in[7];
  const float* b1       = (const float*)d_in[8];
  const float* w_out    = (const float*)d_in[9];
  const float* b_out    = (const float*)d_in[10];
  float* out = (float*)d_out;

  char* ws = (char*)d_ws;
  size_t off = 0;
  auto alloc = [&](size_t bytes) -> void* {
    void* p = ws + off;
    off = (off + bytes + 255) & ~(size_t)255;
    return p;
  };
  unsigned* slots   = (unsigned*)alloc(64 * 16 * sizeof(unsigned));
  unsigned* slots_p = (unsigned*)alloc(64 * 16 * sizeof(unsigned));
  u16* inputs_bf = (u16*)alloc((size_t)NSTEP * BATCH * EMB * 2);
  u16* wih0_bf   = (u16*)alloc((size_t)4 * HID * EMB * 2);
  u16* whh0_bf   = (u16*)alloc((size_t)4 * HID * HID * 2);
  u16* wih1_bf   = (u16*)alloc((size_t)4 * HID * HID * 2);
  u16* whh1_bf   = (u16*)alloc((size_t)4 * HID * HID * 2);
  u16* wout_bf   = (u16*)alloc((size_t)VPAD * HID * 2);
  u16* h0_all    = (u16*)alloc((size_t)NSTEP * BATCH * HID * 2);
  u16* h1_all    = (u16*)alloc((size_t)NSTEP * BATCH * HID * 2);
  u16* A_bf      = (u16*)alloc((size_t)BATCH * SEQT * HID * 2);
  // probe-private buffers
  u16* hp0       = (u16*)alloc((size_t)NSTEP * BATCH * HID * 2);
  u16* hp1       = (u16*)alloc((size_t)NSTEP * BATCH * HID * 2);
  u16* Ap        = (u16*)alloc((size_t)BATCH * SEQT * HID * 2);
  (void)ws_size; (void)in_sizes; (void)n_in; (void)out_size;

  hipFuncSetAttribute((const void*)lstm_pipeline,
                      hipFuncAttributeMaxDynamicSharedMemorySize, LDS_TOTAL);

  hipMemsetAsync(slots, 0, 64 * 16 * sizeof(unsigned), stream);

  {
    int n = NSTEP * BATCH * EMB;
    build_inputs<<<(n + 255) / 256, 256, 0, stream>>>(features, captions, embed_w, inputs_bf);
  }
  {
    int n4 = 4 * HID * EMB / 4;
    cast_bf16<<<(n4 + 255) / 256, 256, 0, stream>>>(w_ih0, wih0_bf, n4);
    cast_bf16<<<(n4 + 255) / 256, 256, 0, stream>>>(w_hh0, whh0_bf, n4);
    cast_bf16<<<(n4 + 255) / 256, 256, 0, stream>>>(w_ih1, wih1_bf, n4);
    cast_bf16<<<(n4 + 255) / 256, 256, 0, stream>>>(w_hh1, whh1_bf, n4);
  }
  {
    int n4 = VPAD * 512 / 4;
    cast_pad_wout<<<(n4 + 255) / 256, 256, 0, stream>>>(w_out, wout_bf);
  }
  // real pipeline
  lstm_pipeline<<<NWG_LSTM, 256, LDS_TOTAL, stream>>>(
      inputs_bf, wih0_bf, whh0_bf, b0, wih1_bf, whh1_bf, b1,
      h0_all, h1_all, A_bf, slots, 1, 1);
  {
    dim3 grid(16, 393, 1);
    logits_gemm<<<grid, 256, 0, stream>>>(A_bf, wout_bf, b_out, out);
  }
  // sync-free probe (diagnostic): 8x65 steps, no polls, private buffers.
  // Output unused; duration read from rocprof top-5.
  lstm_pipeline<<<NWG_LSTM, 256, LDS_TOTAL, stream>>>(
      inputs_bf, wih0_bf, whh0_bf, b0, wih1_bf, whh1_bf, b1,
      hp0, hp1, Ap, slots_p, 8, 0);
}

// Round 6
// 779.133 us; speedup vs baseline: 3.4898x; 3.4898x over previous
//
#include <hip/hip_runtime.h>
#include <stdint.h>
#include <math.h>

// ---------------------------------------------------------------------------
// DecoderRNN: 2-layer LSTM (B=32, T=64, E=H=512) + vocab projection (V=50257)
//
//   K3 lstm_pipeline (rewritten, split-K):
//     64 WGs = 32 slices/layer x 2 layers; slice = 16 h-columns; 4 waves/WG.
//     Wave w owns K-quarter w of concat[x(512); h(512)]:
//       waves 0,1 -> x halves, waves 2,3 -> h halves.
//     Each wave computes PARTIAL gates for all 4 gates x 16 cols x 32 b via
//     mfma 16x16x32 (64 MFMA/wave/step), weights = 128 VGPRs pinned by
//     asm-volatile loads (not rematerializable). A-frags: 16 direct 16B
//     coherent loads/lane (sc0sc1 where producer is another WG). Partials
//     reduced via 32KB LDS; pointwise keeps c-state in VGPRs.
//     Sync: per-WG 64B-padded slot words, wave-scope polls, no fences;
//     h exchanged via atomic-exchange stores (L3 ack) as in round 5.
//   K4 logits_gemm unchanged. Probe (dosync=0) kept, 1x65, private buffers.
// ---------------------------------------------------------------------------

typedef unsigned short u16;
typedef __bf16 bf16x8 __attribute__((ext_vector_type(8)));
typedef float  f32x4  __attribute__((ext_vector_type(4)));

#define BATCH   32
#define SEQT    64
#define NSTEP   65
#define EMB     512
#define HID     512
#define VOCAB   50257
#define VPAD    50304         // 393*128
#define NWG_LSTM 64

static __device__ __forceinline__ u16 f2bf(float f) {
  unsigned u = __float_as_uint(f);
  u += 0x7FFFu + ((u >> 16) & 1u);
  return (u16)(u >> 16);
}

static __device__ __forceinline__ bf16x8 ld_frag(const u16* p16) {
  union { uint4 u; bf16x8 v; } f;
  f.u = *(const uint4*)p16;
  return f.v;
}

// asm 16B loads: result valid only after manual s_waitcnt vmcnt + sched_barrier.
static __device__ __forceinline__ void gload16(uint4* dst, const void* p) {
  asm volatile("global_load_dwordx4 %0, %1, off" : "=v"(*dst) : "v"(p));
}
static __device__ __forceinline__ void gload16_sys(uint4* dst, const void* p) {
  asm volatile("global_load_dwordx4 %0, %1, off sc0 sc1" : "=v"(*dst) : "v"(p));
}
static __device__ __forceinline__ void st_exch64(void* p, unsigned long long v) {
  (void)__hip_atomic_exchange((unsigned long long*)p, v, __ATOMIC_RELAXED,
                              __HIP_MEMORY_SCOPE_AGENT);
}

static __device__ __forceinline__ float sigmoid_fast(float x) {
  return 1.0f / (1.0f + __expf(-x));
}
static __device__ __forceinline__ float tanh_fast(float x) {
  return 1.0f - 2.0f / (__expf(2.0f * x) + 1.0f);
}

// wave-scope slot poll: 32 lanes read 32 slots (64B stride), exit when all>=tgt
static __device__ __forceinline__ void wave_poll(const unsigned* slots,
                                                 int base_slot, unsigned tgt,
                                                 int lane) {
  const unsigned* p = slots + (base_slot + (lane & 31)) * 16;
  for (;;) {
    unsigned v = __hip_atomic_load(p, __ATOMIC_RELAXED, __HIP_MEMORY_SCOPE_AGENT);
    if (__all((int)(v >= tgt))) break;
    __builtin_amdgcn_s_sleep(1);
  }
}

// ---------------------------------------------------------------------------
// K1: compact layout dst[t][e>>4][b][e&15]
// ---------------------------------------------------------------------------
__global__ void build_inputs(const float* __restrict__ features,
                             const int*   __restrict__ captions,
                             const float* __restrict__ embed_w,
                             u16* __restrict__ dst) {
  int idx = blockIdx.x * blockDim.x + threadIdx.x;
  const int n = NSTEP * BATCH * EMB;
  if (idx >= n) return;
  int e = idx & (EMB - 1);
  int rem = idx >> 9;
  int b = rem & (BATCH - 1);
  int t = rem >> 5;
  float v;
  if (t == 0) v = features[b * EMB + e];
  else        v = embed_w[(size_t)captions[b * SEQT + (t - 1)] * EMB + e];
  dst[(size_t)t * 16384 + (e >> 4) * 512 + b * 16 + (e & 15)] = f2bf(v);
}

// ---------------------------------------------------------------------------
// K2
// ---------------------------------------------------------------------------
__global__ void cast_bf16(const float* __restrict__ src, u16* __restrict__ dst, int n4) {
  int i = blockIdx.x * blockDim.x + threadIdx.x;
  if (i >= n4) return;
  float4 v = ((const float4*)src)[i];
  ushort4 o;
  o.x = f2bf(v.x); o.y = f2bf(v.y); o.z = f2bf(v.z); o.w = f2bf(v.w);
  ((ushort4*)dst)[i] = o;
}

__global__ void cast_pad_wout(const float* __restrict__ src, u16* __restrict__ dst) {
  int i = blockIdx.x * blockDim.x + threadIdx.x;
  const int n4 = VPAD * 512 / 4;
  const int nsrc4 = VOCAB * 512 / 4;
  if (i >= n4) return;
  ushort4 o;
  if (i < nsrc4) {
    float4 v = ((const float4*)src)[i];
    o.x = f2bf(v.x); o.y = f2bf(v.y); o.z = f2bf(v.z); o.w = f2bf(v.w);
  } else {
    o.x = 0; o.y = 0; o.z = 0; o.w = 0;
  }
  ((ushort4*)dst)[i] = o;
}

// ---------------------------------------------------------------------------
// K3: split-K persistent LSTM
// ---------------------------------------------------------------------------
#define WAITVM(N) do { asm volatile("s_waitcnt vmcnt(" #N ")" ::: "memory"); \
                       __builtin_amdgcn_sched_barrier(0); } while (0)

__global__ __launch_bounds__(256, 1)
void lstm_pipeline(const u16* __restrict__ inputs_bf,   // [65][32sl][32b][16]
                   const u16* __restrict__ wih0, const u16* __restrict__ whh0,
                   const float* __restrict__ b0,
                   const u16* __restrict__ wih1, const u16* __restrict__ whh1,
                   const float* __restrict__ b1,
                   u16* h0_all,                  // [65][32sl][32b][16]
                   u16* h1_all,
                   u16* __restrict__ A_bf,       // [2048][512] rows (b*64+t)
                   unsigned* slots,              // [64] x 16 u32
                   int dosync) {
  const int wg    = blockIdx.x;
  const int layer = wg >> 5;
  const int jsl   = wg & 31;
  const int j0    = jsl * 16;
  const int tid   = threadIdx.x;
  const int lane  = tid & 63;
  const int wv    = tid >> 6;       // wave = K-quarter of [x;h]
  const int l15   = lane & 15;
  const int lg    = lane >> 4;
  const bool is_h = (wv >= 2);      // waves 2,3 consume h[t-1]
  const int  wq   = wv & 1;         // K-half within the matrix

  const u16*   wih  = layer ? wih1 : wih0;
  const u16*   whh  = layer ? whh1 : whh0;
  const float* bias = layer ? b1 : b0;
  const char* xsrc0 = (const char*)(layer ? h0_all : inputs_bf);
  const char* hsrc0 = (const char*)(layer ? h1_all : h0_all);
  u16*        hdst  = layer ? h1_all : h0_all;
  const int own_base = layer ? 32 : 0;

  __shared__ float gparts[4][4][512];   // [wave][gate][b*16+jj], 32 KB
  __shared__ float bias_l[64];          // [g*16+jj]

  if (tid < 64) bias_l[tid] = bias[(tid >> 4) * HID + j0 + (tid & 15)];

  // ---- weights: 32 fragments (128 VGPRs), pinned via asm-volatile loads ----
  // wave wv: matrix = (is_h ? whh : wih), k-range [wq*256, wq*256+256)
  // frag[kc][g4]: 16B = W[g4*512 + j0 + l15][wq*256 + kc*32 + 8*lg .. +7]
  uint4 wreg[8][4];
  {
    const u16* wmat = is_h ? whh : wih;
    const int  kb   = wq * 256;
#pragma unroll
    for (int kc = 0; kc < 8; ++kc) {
#pragma unroll
      for (int g4 = 0; g4 < 4; ++g4) {
        gload16(&wreg[kc][g4],
                wmat + (size_t)(g4 * 512 + j0 + l15) * 512 + kb + kc * 32 + 8 * lg);
      }
      WAITVM(0);   // setup-time; keep in-flight count tiny to avoid spill hazard
    }
  }
  __syncthreads();

  // per-lane A-frag base byte offset within a [32sl][32b][16] tile:
  // frag(bh,kc) at laoff + kc*2048 + bh*512
  const int laoff = wq * 16384 + (lg >> 1) * 1024 + l15 * 32 + (lg & 1) * 16;

  // c-state in VGPRs of pointwise threads (tid<128): (b=tid>>2, jj=(tid&3)*4+u)
  float creg[4] = {0.f, 0.f, 0.f, 0.f};

  for (int t = 0; t < NSTEP; ++t) {
    f32x4 acc[2][4];
#pragma unroll
    for (int bh = 0; bh < 2; ++bh)
#pragma unroll
      for (int g4 = 0; g4 < 4; ++g4) acc[bh][g4] = (f32x4){0.f, 0.f, 0.f, 0.f};

    const bool have_a = is_h ? (t > 0) : true;
    if (have_a) {
      const char* src;
      bool sys;
      if (!is_h) {
        src = xsrc0 + (size_t)t * 32768;
        sys = (layer == 1);
        if (layer == 1 && dosync) wave_poll(slots, 0, (unsigned)(t + 1), lane);
      } else {
        src = hsrc0 + (size_t)(t - 1) * 32768;
        sys = true;
        if (dosync) wave_poll(slots, own_base, (unsigned)t, lane);
      }
      uint4 areg[2][8];
      if (sys) {
#pragma unroll
        for (int kc = 0; kc < 8; ++kc) gload16_sys(&areg[0][kc], src + laoff + kc * 2048);
#pragma unroll
        for (int kc = 0; kc < 8; ++kc) gload16_sys(&areg[1][kc], src + laoff + kc * 2048 + 512);
      } else {
#pragma unroll
        for (int kc = 0; kc < 8; ++kc) gload16(&areg[0][kc], src + laoff + kc * 2048);
#pragma unroll
        for (int kc = 0; kc < 8; ++kc) gload16(&areg[1][kc], src + laoff + kc * 2048 + 512);
      }
      WAITVM(8);   // bh=0 group ready
#pragma unroll
      for (int kc = 0; kc < 8; ++kc)
#pragma unroll
        for (int g4 = 0; g4 < 4; ++g4)
          acc[0][g4] = __builtin_amdgcn_mfma_f32_16x16x32_bf16(
              *(const bf16x8*)&areg[0][kc], *(const bf16x8*)&wreg[kc][g4],
              acc[0][g4], 0, 0, 0);
      WAITVM(0);   // bh=1 group ready
#pragma unroll
      for (int kc = 0; kc < 8; ++kc)
#pragma unroll
        for (int g4 = 0; g4 < 4; ++g4)
          acc[1][g4] = __builtin_amdgcn_mfma_f32_16x16x32_bf16(
              *(const bf16x8*)&areg[1][kc], *(const bf16x8*)&wreg[kc][g4],
              acc[1][g4], 0, 0, 0);
    }
    // partial gates -> LDS. C layout: col(l15)=gate-col, row=4*lg+rr within b-half
#pragma unroll
    for (int bh = 0; bh < 2; ++bh)
#pragma unroll
      for (int g4 = 0; g4 < 4; ++g4)
#pragma unroll
        for (int rr = 0; rr < 4; ++rr)
          gparts[wv][g4][(bh * 16 + 4 * lg + rr) * 16 + l15] = acc[bh][g4][rr];
    __syncthreads();

    if (tid < 128) {
      const int b = tid >> 2, jq = tid & 3;
      float hv[4];
#pragma unroll
      for (int u = 0; u < 4; ++u) {
        const int jj = jq * 4 + u;
        float gi = bias_l[0 * 16 + jj];
        float gf = bias_l[1 * 16 + jj];
        float gg = bias_l[2 * 16 + jj];
        float go = bias_l[3 * 16 + jj];
#pragma unroll
        for (int w = 0; w < 4; ++w) {
          gi += gparts[w][0][b * 16 + jj];
          gf += gparts[w][1][b * 16 + jj];
          gg += gparts[w][2][b * 16 + jj];
          go += gparts[w][3][b * 16 + jj];
        }
        float cn = sigmoid_fast(gf) * creg[u] + sigmoid_fast(gi) * tanh_fast(gg);
        creg[u] = cn;
        hv[u] = sigmoid_fast(go) * tanh_fast(cn);
      }
      union { ushort4 s; unsigned long long v; } pk;
      pk.s.x = f2bf(hv[0]); pk.s.y = f2bf(hv[1]);
      pk.s.z = f2bf(hv[2]); pk.s.w = f2bf(hv[3]);
      st_exch64((char*)hdst + (size_t)t * 32768 + jsl * 1024 + b * 32 + jq * 8, pk.v);
      if (layer == 1 && t >= 1)
        *(unsigned long long*)(A_bf + (size_t)(b * SEQT + (t - 1)) * HID + j0 + jq * 4) = pk.v;
    }
    asm volatile("s_waitcnt vmcnt(0)" ::: "memory");   // drain h stores (L3 ack)
    __syncthreads();
    if (tid == 0)
      (void)__hip_atomic_exchange(&slots[wg * 16], (unsigned)(t + 1),
                                  __ATOMIC_RELAXED, __HIP_MEMORY_SCOPE_AGENT);
  }
}

// ---------------------------------------------------------------------------
// K4: logits GEMM (unchanged).
// ---------------------------------------------------------------------------
__global__ __launch_bounds__(256)
void logits_gemm(const u16* __restrict__ Ag,
                 const u16* __restrict__ Bg,
                 const float* __restrict__ b_out,
                 float* __restrict__ out) {
  const int mt = blockIdx.x;
  const int nt = blockIdx.y;
  const int m0 = mt * 128, v0 = nt * 128;
  const int tid  = threadIdx.x;
  const int lane = tid & 63;
  const int wv   = tid >> 6;
  const int l15  = lane & 15;
  const int lg   = lane >> 4;
  const int wm = (wv & 1) * 64;
  const int wn = (wv >> 1) * 64;

  __shared__ u16 As[128 * 32];
  __shared__ u16 Bs[128 * 32];

  f32x4 acc[4][4];
#pragma unroll
  for (int mi = 0; mi < 4; ++mi)
#pragma unroll
    for (int ni = 0; ni < 4; ++ni)
      acc[mi][ni] = (f32x4){0.f, 0.f, 0.f, 0.f};

  for (int kt = 0; kt < 16; ++kt) {
#pragma unroll
    for (int c = 0; c < 2; ++c) {
      int f16 = wv * 128 + c * 64 + lane;
      int row = f16 >> 2;
      int kc  = (f16 & 3) << 3;
      const u16* ga = Ag + (size_t)(m0 + row) * 512 + kt * 32 + kc;
      const u16* gb = Bg + (size_t)(v0 + row) * 512 + kt * 32 + kc;
      u16* la = &As[(wv * 128 + c * 64) * 8];
      u16* lb = &Bs[(wv * 128 + c * 64) * 8];
      __builtin_amdgcn_global_load_lds(
          (const __attribute__((address_space(1))) void*)ga,
          (__attribute__((address_space(3))) void*)la, 16, 0, 0);
      __builtin_amdgcn_global_load_lds(
          (const __attribute__((address_space(1))) void*)gb,
          (__attribute__((address_space(3))) void*)lb, 16, 0, 0);
    }
    asm volatile("s_waitcnt vmcnt(0)" ::: "memory");
    __syncthreads();

    bf16x8 af[4], bfr[4];
#pragma unroll
    for (int i = 0; i < 4; ++i) {
      af[i]  = ld_frag(&As[(wm + i * 16 + l15) * 32 + 8 * lg]);
      bfr[i] = ld_frag(&Bs[(wn + i * 16 + l15) * 32 + 8 * lg]);
    }
#pragma unroll
    for (int mi = 0; mi < 4; ++mi)
#pragma unroll
      for (int ni = 0; ni < 4; ++ni)
        acc[mi][ni] = __builtin_amdgcn_mfma_f32_16x16x32_bf16(af[mi], bfr[ni], acc[mi][ni], 0, 0, 0);
    __syncthreads();
  }

#pragma unroll
  for (int ni = 0; ni < 4; ++ni) {
    int v = v0 + wn + ni * 16 + l15;
    bool vok = (v < VOCAB);
    float bo = vok ? b_out[v] : 0.0f;
#pragma unroll
    for (int mi = 0; mi < 4; ++mi) {
      int mbase = m0 + wm + mi * 16 + 4 * lg;
#pragma unroll
      for (int rr = 0; rr < 4; ++rr) {
        if (vok) out[(size_t)(mbase + rr) * VOCAB + v] = acc[mi][ni][rr] + bo;
      }
    }
  }
}

// ---------------------------------------------------------------------------
// host
// ---------------------------------------------------------------------------
extern "C" void kernel_launch(void* const* d_in, const int* in_sizes, int n_in,
                              void* d_out, int out_size, void* d_ws, size_t ws_size,
                              hipStream_t stream) {
  const float* features = (const float*)d_in[0];
  const int*   captions = (const int*)d_in[1];
  const float* embed_w  = (const float*)d_in[2];
  const float* w_ih0    = (const float*)d_in[3];
  const float* w_hh0    = (const float*)d_in[4];
  const float* b0       = (const float*)d_in[5];
  const float* w_ih1    = (const float*)d_in[6];
  const float* w_hh1    = (const float*)d_in[7];
  const float* b1       = (const float*)d_in[8];
  const float* w_out    = (const float*)d_in[9];
  const float* b_out    = (const float*)d_in[10];
  float* out = (float*)d_out;

  char* ws = (char*)d_ws;
  size_t off = 0;
  auto alloc = [&](size_t bytes) -> void* {
    void* p = ws + off;
    off = (off + bytes + 255) & ~(size_t)255;
    return p;
  };
  unsigned* slots   = (unsigned*)alloc(64 * 16 * sizeof(unsigned));
  unsigned* slots_p = (unsigned*)alloc(64 * 16 * sizeof(unsigned));
  u16* inputs_bf = (u16*)alloc((size_t)NSTEP * BATCH * EMB * 2);
  u16* wih0_bf   = (u16*)alloc((size_t)4 * HID * EMB * 2);
  u16* whh0_bf   = (u16*)alloc((size_t)4 * HID * HID * 2);
  u16* wih1_bf   = (u16*)alloc((size_t)4 * HID * HID * 2);
  u16* whh1_bf   = (u16*)alloc((size_t)4 * HID * HID * 2);
  u16* wout_bf   = (u16*)alloc((size_t)VPAD * HID * 2);
  u16* h0_all    = (u16*)alloc((size_t)NSTEP * BATCH * HID * 2);
  u16* h1_all    = (u16*)alloc((size_t)NSTEP * BATCH * HID * 2);
  u16* A_bf      = (u16*)alloc((size_t)BATCH * SEQT * HID * 2);
  u16* hp0       = (u16*)alloc((size_t)NSTEP * BATCH * HID * 2);
  u16* hp1       = (u16*)alloc((size_t)NSTEP * BATCH * HID * 2);
  u16* Ap        = (u16*)alloc((size_t)BATCH * SEQT * HID * 2);
  (void)ws_size; (void)in_sizes; (void)n_in; (void)out_size;

  hipMemsetAsync(slots, 0, 64 * 16 * sizeof(unsigned), stream);

  {
    int n = NSTEP * BATCH * EMB;
    build_inputs<<<(n + 255) / 256, 256, 0, stream>>>(features, captions, embed_w, inputs_bf);
  }
  {
    int n4 = 4 * HID * EMB / 4;
    cast_bf16<<<(n4 + 255) / 256, 256, 0, stream>>>(w_ih0, wih0_bf, n4);
    cast_bf16<<<(n4 + 255) / 256, 256, 0, stream>>>(w_hh0, whh0_bf, n4);
    cast_bf16<<<(n4 + 255) / 256, 256, 0, stream>>>(w_ih1, wih1_bf, n4);
    cast_bf16<<<(n4 + 255) / 256, 256, 0, stream>>>(w_hh1, whh1_bf, n4);
  }
  {
    int n4 = VPAD * 512 / 4;
    cast_pad_wout<<<(n4 + 255) / 256, 256, 0, stream>>>(w_out, wout_bf);
  }
  // real pipeline
  lstm_pipeline<<<NWG_LSTM, 256, 0, stream>>>(
      inputs_bf, wih0_bf, whh0_bf, b0, wih1_bf, whh1_bf, b1,
      h0_all, h1_all, A_bf, slots, 1);
  {
    dim3 grid(16, 393, 1);
    logits_gemm<<<grid, 256, 0, stream>>>(A_bf, wout_bf, b_out, out);
  }
  // sync-free probe (diagnostic, 1x65, private buffers): compute floor via rocprof
  lstm_pipeline<<<NWG_LSTM, 256, 0, stream>>>(
      inputs_bf, wih0_bf, whh0_bf, b0, wih1_bf, whh1_bf, b1,
      hp0, hp1, Ap, slots_p, 0);
}

// Round 7
// 528.956 us; speedup vs baseline: 5.1404x; 1.4730x over previous
//
#include <hip/hip_runtime.h>
#include <stdint.h>
#include <math.h>

// ---------------------------------------------------------------------------
// DecoderRNN: 2-layer LSTM (B=32, T=64, E=H=512) + vocab projection (V=50257)
//
//   K3 lstm_pipeline: split-K persistent LSTM (round-6 structure, unchanged).
//   K4 logits_gemm  : 128x128xBK64 bf16 MFMA GEMM, XCD-swizzled grid
//       (6288 = 8*786 bijective), T2 XOR-swizzled LDS (pre-swizzled
//       global_load_lds source + swizzled ds_read), f32 out + bias.
//   Probe removed (diagnosis done: sync ~25%, work ~75%; split-K fixed work).
// ---------------------------------------------------------------------------

typedef unsigned short u16;
typedef __bf16 bf16x8 __attribute__((ext_vector_type(8)));
typedef float  f32x4  __attribute__((ext_vector_type(4)));

#define BATCH   32
#define SEQT    64
#define NSTEP   65
#define EMB     512
#define HID     512
#define VOCAB   50257
#define VPAD    50304         // 393*128
#define NWG_LSTM 64

static __device__ __forceinline__ u16 f2bf(float f) {
  unsigned u = __float_as_uint(f);
  u += 0x7FFFu + ((u >> 16) & 1u);
  return (u16)(u >> 16);
}

static __device__ __forceinline__ bf16x8 ld_frag(const u16* p16) {
  union { uint4 u; bf16x8 v; } f;
  f.u = *(const uint4*)p16;
  return f.v;
}

// asm 16B loads: result valid only after manual s_waitcnt vmcnt + sched_barrier.
static __device__ __forceinline__ void gload16(uint4* dst, const void* p) {
  asm volatile("global_load_dwordx4 %0, %1, off" : "=v"(*dst) : "v"(p));
}
static __device__ __forceinline__ void gload16_sys(uint4* dst, const void* p) {
  asm volatile("global_load_dwordx4 %0, %1, off sc0 sc1" : "=v"(*dst) : "v"(p));
}
static __device__ __forceinline__ void st_exch64(void* p, unsigned long long v) {
  (void)__hip_atomic_exchange((unsigned long long*)p, v, __ATOMIC_RELAXED,
                              __HIP_MEMORY_SCOPE_AGENT);
}

static __device__ __forceinline__ float sigmoid_fast(float x) {
  return 1.0f / (1.0f + __expf(-x));
}
static __device__ __forceinline__ float tanh_fast(float x) {
  return 1.0f - 2.0f / (__expf(2.0f * x) + 1.0f);
}

static __device__ __forceinline__ void wave_poll(const unsigned* slots,
                                                 int base_slot, unsigned tgt,
                                                 int lane) {
  const unsigned* p = slots + (base_slot + (lane & 31)) * 16;
  for (;;) {
    unsigned v = __hip_atomic_load(p, __ATOMIC_RELAXED, __HIP_MEMORY_SCOPE_AGENT);
    if (__all((int)(v >= tgt))) break;
    __builtin_amdgcn_s_sleep(1);
  }
}

// ---------------------------------------------------------------------------
// K1: compact layout dst[t][e>>4][b][e&15]
// ---------------------------------------------------------------------------
__global__ void build_inputs(const float* __restrict__ features,
                             const int*   __restrict__ captions,
                             const float* __restrict__ embed_w,
                             u16* __restrict__ dst) {
  int idx = blockIdx.x * blockDim.x + threadIdx.x;
  const int n = NSTEP * BATCH * EMB;
  if (idx >= n) return;
  int e = idx & (EMB - 1);
  int rem = idx >> 9;
  int b = rem & (BATCH - 1);
  int t = rem >> 5;
  float v;
  if (t == 0) v = features[b * EMB + e];
  else        v = embed_w[(size_t)captions[b * SEQT + (t - 1)] * EMB + e];
  dst[(size_t)t * 16384 + (e >> 4) * 512 + b * 16 + (e & 15)] = f2bf(v);
}

// ---------------------------------------------------------------------------
// K2
// ---------------------------------------------------------------------------
__global__ void cast_bf16(const float* __restrict__ src, u16* __restrict__ dst, int n4) {
  int i = blockIdx.x * blockDim.x + threadIdx.x;
  if (i >= n4) return;
  float4 v = ((const float4*)src)[i];
  ushort4 o;
  o.x = f2bf(v.x); o.y = f2bf(v.y); o.z = f2bf(v.z); o.w = f2bf(v.w);
  ((ushort4*)dst)[i] = o;
}

__global__ void cast_pad_wout(const float* __restrict__ src, u16* __restrict__ dst) {
  int i = blockIdx.x * blockDim.x + threadIdx.x;
  const int n4 = VPAD * 512 / 4;
  const int nsrc4 = VOCAB * 512 / 4;
  if (i >= n4) return;
  ushort4 o;
  if (i < nsrc4) {
    float4 v = ((const float4*)src)[i];
    o.x = f2bf(v.x); o.y = f2bf(v.y); o.z = f2bf(v.z); o.w = f2bf(v.w);
  } else {
    o.x = 0; o.y = 0; o.z = 0; o.w = 0;
  }
  ((ushort4*)dst)[i] = o;
}

// ---------------------------------------------------------------------------
// K3: split-K persistent LSTM (unchanged from round 6)
// ---------------------------------------------------------------------------
#define WAITVM(N) do { asm volatile("s_waitcnt vmcnt(" #N ")" ::: "memory"); \
                       __builtin_amdgcn_sched_barrier(0); } while (0)

__global__ __launch_bounds__(256, 1)
void lstm_pipeline(const u16* __restrict__ inputs_bf,   // [65][32sl][32b][16]
                   const u16* __restrict__ wih0, const u16* __restrict__ whh0,
                   const float* __restrict__ b0,
                   const u16* __restrict__ wih1, const u16* __restrict__ whh1,
                   const float* __restrict__ b1,
                   u16* h0_all, u16* h1_all,
                   u16* __restrict__ A_bf,       // [2048][512] rows (b*64+t)
                   unsigned* slots, int dosync) {
  const int wg    = blockIdx.x;
  const int layer = wg >> 5;
  const int jsl   = wg & 31;
  const int j0    = jsl * 16;
  const int tid   = threadIdx.x;
  const int lane  = tid & 63;
  const int wv    = tid >> 6;
  const int l15   = lane & 15;
  const int lg    = lane >> 4;
  const bool is_h = (wv >= 2);
  const int  wq   = wv & 1;

  const u16*   wih  = layer ? wih1 : wih0;
  const u16*   whh  = layer ? whh1 : whh0;
  const float* bias = layer ? b1 : b0;
  const char* xsrc0 = (const char*)(layer ? h0_all : inputs_bf);
  const char* hsrc0 = (const char*)(layer ? h1_all : h0_all);
  u16*        hdst  = layer ? h1_all : h0_all;
  const int own_base = layer ? 32 : 0;

  __shared__ float gparts[4][4][512];
  __shared__ float bias_l[64];

  if (tid < 64) bias_l[tid] = bias[(tid >> 4) * HID + j0 + (tid & 15)];

  uint4 wreg[8][4];
  {
    const u16* wmat = is_h ? whh : wih;
    const int  kb   = wq * 256;
#pragma unroll
    for (int kc = 0; kc < 8; ++kc) {
#pragma unroll
      for (int g4 = 0; g4 < 4; ++g4) {
        gload16(&wreg[kc][g4],
                wmat + (size_t)(g4 * 512 + j0 + l15) * 512 + kb + kc * 32 + 8 * lg);
      }
      WAITVM(0);
    }
  }
  __syncthreads();

  const int laoff = wq * 16384 + (lg >> 1) * 1024 + l15 * 32 + (lg & 1) * 16;
  float creg[4] = {0.f, 0.f, 0.f, 0.f};

  for (int t = 0; t < NSTEP; ++t) {
    f32x4 acc[2][4];
#pragma unroll
    for (int bh = 0; bh < 2; ++bh)
#pragma unroll
      for (int g4 = 0; g4 < 4; ++g4) acc[bh][g4] = (f32x4){0.f, 0.f, 0.f, 0.f};

    const bool have_a = is_h ? (t > 0) : true;
    if (have_a) {
      const char* src;
      bool sys;
      if (!is_h) {
        src = xsrc0 + (size_t)t * 32768;
        sys = (layer == 1);
        if (layer == 1 && dosync) wave_poll(slots, 0, (unsigned)(t + 1), lane);
      } else {
        src = hsrc0 + (size_t)(t - 1) * 32768;
        sys = true;
        if (dosync) wave_poll(slots, own_base, (unsigned)t, lane);
      }
      uint4 areg[2][8];
      if (sys) {
#pragma unroll
        for (int kc = 0; kc < 8; ++kc) gload16_sys(&areg[0][kc], src + laoff + kc * 2048);
#pragma unroll
        for (int kc = 0; kc < 8; ++kc) gload16_sys(&areg[1][kc], src + laoff + kc * 2048 + 512);
      } else {
#pragma unroll
        for (int kc = 0; kc < 8; ++kc) gload16(&areg[0][kc], src + laoff + kc * 2048);
#pragma unroll
        for (int kc = 0; kc < 8; ++kc) gload16(&areg[1][kc], src + laoff + kc * 2048 + 512);
      }
      WAITVM(8);
#pragma unroll
      for (int kc = 0; kc < 8; ++kc)
#pragma unroll
        for (int g4 = 0; g4 < 4; ++g4)
          acc[0][g4] = __builtin_amdgcn_mfma_f32_16x16x32_bf16(
              *(const bf16x8*)&areg[0][kc], *(const bf16x8*)&wreg[kc][g4],
              acc[0][g4], 0, 0, 0);
      WAITVM(0);
#pragma unroll
      for (int kc = 0; kc < 8; ++kc)
#pragma unroll
        for (int g4 = 0; g4 < 4; ++g4)
          acc[1][g4] = __builtin_amdgcn_mfma_f32_16x16x32_bf16(
              *(const bf16x8*)&areg[1][kc], *(const bf16x8*)&wreg[kc][g4],
              acc[1][g4], 0, 0, 0);
    }
#pragma unroll
    for (int bh = 0; bh < 2; ++bh)
#pragma unroll
      for (int g4 = 0; g4 < 4; ++g4)
#pragma unroll
        for (int rr = 0; rr < 4; ++rr)
          gparts[wv][g4][(bh * 16 + 4 * lg + rr) * 16 + l15] = acc[bh][g4][rr];
    __syncthreads();

    if (tid < 128) {
      const int b = tid >> 2, jq = tid & 3;
      float hv[4];
#pragma unroll
      for (int u = 0; u < 4; ++u) {
        const int jj = jq * 4 + u;
        float gi = bias_l[0 * 16 + jj];
        float gf = bias_l[1 * 16 + jj];
        float gg = bias_l[2 * 16 + jj];
        float go = bias_l[3 * 16 + jj];
#pragma unroll
        for (int w = 0; w < 4; ++w) {
          gi += gparts[w][0][b * 16 + jj];
          gf += gparts[w][1][b * 16 + jj];
          gg += gparts[w][2][b * 16 + jj];
          go += gparts[w][3][b * 16 + jj];
        }
        float cn = sigmoid_fast(gf) * creg[u] + sigmoid_fast(gi) * tanh_fast(gg);
        creg[u] = cn;
        hv[u] = sigmoid_fast(go) * tanh_fast(cn);
      }
      union { ushort4 s; unsigned long long v; } pk;
      pk.s.x = f2bf(hv[0]); pk.s.y = f2bf(hv[1]);
      pk.s.z = f2bf(hv[2]); pk.s.w = f2bf(hv[3]);
      st_exch64((char*)hdst + (size_t)t * 32768 + jsl * 1024 + b * 32 + jq * 8, pk.v);
      if (layer == 1 && t >= 1)
        *(unsigned long long*)(A_bf + (size_t)(b * SEQT + (t - 1)) * HID + j0 + jq * 4) = pk.v;
    }
    asm volatile("s_waitcnt vmcnt(0)" ::: "memory");
    __syncthreads();
    if (tid == 0)
      (void)__hip_atomic_exchange(&slots[wg * 16], (unsigned)(t + 1),
                                  __ATOMIC_RELAXED, __HIP_MEMORY_SCOPE_AGENT);
  }
}

// ---------------------------------------------------------------------------
// K4: logits GEMM. 128x128 tile, BK=64, XCD-swizzled grid, T2 LDS swizzle.
// ---------------------------------------------------------------------------
__global__ __launch_bounds__(256)
void logits_gemm(const u16* __restrict__ Ag,
                 const u16* __restrict__ Bg,
                 const float* __restrict__ b_out,
                 float* __restrict__ out) {
  // bijective XCD swizzle: nwg = 6288 = 8 * 786 (divisible -> simple form)
  const int bid = blockIdx.x;
  const int lin = (bid & 7) * 786 + (bid >> 3);
  const int mt = lin & 15;          // m-index fastest within an XCD chunk
  const int nt = lin >> 4;
  const int m0 = mt * 128, v0 = nt * 128;
  const int tid  = threadIdx.x;
  const int lane = tid & 63;
  const int wv   = tid >> 6;
  const int l15  = lane & 15;
  const int lg   = lane >> 4;
  const int wm = (wv & 1) * 64;
  const int wn = (wv >> 1) * 64;

  __shared__ u16 As[128 * 64];   // 16 KB, row stride 128 B, XOR-swizzled
  __shared__ u16 Bs[128 * 64];   // 16 KB

  f32x4 acc[4][4];
#pragma unroll
  for (int mi = 0; mi < 4; ++mi)
#pragma unroll
    for (int ni = 0; ni < 4; ++ni)
      acc[mi][ni] = (f32x4){0.f, 0.f, 0.f, 0.f};

  const int rswz = (l15 & 7) << 3;   // read-side XOR, u16 elements

  for (int kt = 0; kt < 8; ++kt) {
    // stage 128x64 A and B; source pre-swizzled so linear LDS dest ends up
    // swizzled (rule #21): chunk (row, kc) holds global k-chunk kc^(row&7)
#pragma unroll
    for (int c = 0; c < 4; ++c) {
      int chunk = wv * 256 + c * 64 + lane;   // 16B-chunk id, 1024/matrix
      int row   = chunk >> 3;                 // 8 chunks (128B) per row
      int kcs   = ((chunk & 7) ^ (row & 7)) << 3;   // u16 elements
      const u16* ga = Ag + (size_t)(m0 + row) * 512 + kt * 64 + kcs;
      const u16* gb = Bg + (size_t)(v0 + row) * 512 + kt * 64 + kcs;
      u16* la = &As[(wv * 256 + c * 64) * 8];
      u16* lb = &Bs[(wv * 256 + c * 64) * 8];
      __builtin_amdgcn_global_load_lds(
          (const __attribute__((address_space(1))) void*)ga,
          (__attribute__((address_space(3))) void*)la, 16, 0, 0);
      __builtin_amdgcn_global_load_lds(
          (const __attribute__((address_space(1))) void*)gb,
          (__attribute__((address_space(3))) void*)lb, 16, 0, 0);
    }
    asm volatile("s_waitcnt vmcnt(0)" ::: "memory");
    __syncthreads();

    bf16x8 af[2][4], bfr[2][4];
#pragma unroll
    for (int ks = 0; ks < 2; ++ks)
#pragma unroll
      for (int i = 0; i < 4; ++i) {
        af[ks][i]  = ld_frag(&As[(wm + i * 16 + l15) * 64 + ((ks * 32 + 8 * lg) ^ rswz)]);
        bfr[ks][i] = ld_frag(&Bs[(wn + i * 16 + l15) * 64 + ((ks * 32 + 8 * lg) ^ rswz)]);
      }
#pragma unroll
    for (int ks = 0; ks < 2; ++ks)
#pragma unroll
      for (int mi = 0; mi < 4; ++mi)
#pragma unroll
        for (int ni = 0; ni < 4; ++ni)
          acc[mi][ni] = __builtin_amdgcn_mfma_f32_16x16x32_bf16(
              af[ks][mi], bfr[ks][ni], acc[mi][ni], 0, 0, 0);
    __syncthreads();
  }

  // epilogue: C row = 4*lg + rr (m), col = l15 (v)
#pragma unroll
  for (int ni = 0; ni < 4; ++ni) {
    int v = v0 + wn + ni * 16 + l15;
    bool vok = (v < VOCAB);
    float bo = vok ? b_out[v] : 0.0f;
#pragma unroll
    for (int mi = 0; mi < 4; ++mi) {
      int mbase = m0 + wm + mi * 16 + 4 * lg;
#pragma unroll
      for (int rr = 0; rr < 4; ++rr) {
        if (vok) out[(size_t)(mbase + rr) * VOCAB + v] = acc[mi][ni][rr] + bo;
      }
    }
  }
}

// ---------------------------------------------------------------------------
// host
// ---------------------------------------------------------------------------
extern "C" void kernel_launch(void* const* d_in, const int* in_sizes, int n_in,
                              void* d_out, int out_size, void* d_ws, size_t ws_size,
                              hipStream_t stream) {
  const float* features = (const float*)d_in[0];
  const int*   captions = (const int*)d_in[1];
  const float* embed_w  = (const float*)d_in[2];
  const float* w_ih0    = (const float*)d_in[3];
  const float* w_hh0    = (const float*)d_in[4];
  const float* b0       = (const float*)d_in[5];
  const float* w_ih1    = (const float*)d_in[6];
  const float* w_hh1    = (const float*)d_in[7];
  const float* b1       = (const float*)d_in[8];
  const float* w_out    = (const float*)d_in[9];
  const float* b_out    = (const float*)d_in[10];
  float* out = (float*)d_out;

  char* ws = (char*)d_ws;
  size_t off = 0;
  auto alloc = [&](size_t bytes) -> void* {
    void* p = ws + off;
    off = (off + bytes + 255) & ~(size_t)255;
    return p;
  };
  unsigned* slots = (unsigned*)alloc(64 * 16 * sizeof(unsigned));
  u16* inputs_bf = (u16*)alloc((size_t)NSTEP * BATCH * EMB * 2);
  u16* wih0_bf   = (u16*)alloc((size_t)4 * HID * EMB * 2);
  u16* whh0_bf   = (u16*)alloc((size_t)4 * HID * HID * 2);
  u16* wih1_bf   = (u16*)alloc((size_t)4 * HID * HID * 2);
  u16* whh1_bf   = (u16*)alloc((size_t)4 * HID * HID * 2);
  u16* wout_bf   = (u16*)alloc((size_t)VPAD * HID * 2);
  u16* h0_all    = (u16*)alloc((size_t)NSTEP * BATCH * HID * 2);
  u16* h1_all    = (u16*)alloc((size_t)NSTEP * BATCH * HID * 2);
  u16* A_bf      = (u16*)alloc((size_t)BATCH * SEQT * HID * 2);
  (void)ws_size; (void)in_sizes; (void)n_in; (void)out_size;

  hipMemsetAsync(slots, 0, 64 * 16 * sizeof(unsigned), stream);

  {
    int n = NSTEP * BATCH * EMB;
    build_inputs<<<(n + 255) / 256, 256, 0, stream>>>(features, captions, embed_w, inputs_bf);
  }
  {
    int n4 = 4 * HID * EMB / 4;
    cast_bf16<<<(n4 + 255) / 256, 256, 0, stream>>>(w_ih0, wih0_bf, n4);
    cast_bf16<<<(n4 + 255) / 256, 256, 0, stream>>>(w_hh0, whh0_bf, n4);
    cast_bf16<<<(n4 + 255) / 256, 256, 0, stream>>>(w_ih1, wih1_bf, n4);
    cast_bf16<<<(n4 + 255) / 256, 256, 0, stream>>>(w_hh1, whh1_bf, n4);
  }
  {
    int n4 = VPAD * 512 / 4;
    cast_pad_wout<<<(n4 + 255) / 256, 256, 0, stream>>>(w_out, wout_bf);
  }
  lstm_pipeline<<<NWG_LSTM, 256, 0, stream>>>(
      inputs_bf, wih0_bf, whh0_bf, b0, wih1_bf, whh1_bf, b1,
      h0_all, h1_all, A_bf, slots, 1);
  {
    logits_gemm<<<16 * 393, 256, 0, stream>>>(A_bf, wout_bf, b_out, out);
  }
}